// Round 3
// baseline (2102.548 us; speedup 1.0000x reference)
//
#include <hip/hip_runtime.h>
#include <hip/hip_bf16.h>
#include <math.h>

// SharedLora on MI355X — round 3.
// k_w computes w AND the KL quadratic in one pass over the gathered deltas
// using the Gram trick: sum_c (sum_a C[a,c] x_a)^2 = x^T (C C^T) x.
// Per-level 20-vectors x are in registers while building the level-sum U,
// so the KL needs no second pass (k_kl deleted, -320 MB traffic).
// U/output kept in registers (thread = one pair of bins, all 20 clusters);
// w stored bf16 (82 MB, L3-resident for the gather).

#define NROI 256
#define NC 20
#define NFINAL 8000
#define NCUTS 500000
#define NTILE 8            // tiles per region
#define TBINS 1000         // bins per tile

// q += x^T G x  (G_sh in LDS, broadcast reads)
#define QUADG(x)                                          \
    do {                                                  \
        _Pragma("unroll")                                 \
        for (int a_ = 0; a_ < 20; a_++) {                 \
            float t_ = 0.f;                               \
            _Pragma("unroll")                             \
            for (int b_ = 0; b_ < 20; b_++)               \
                t_ += G_sh[a_ * 20 + b_] * x[b_];         \
            q += x[a_] * t_;                              \
        }                                                 \
    } while (0)

__global__ void k_init(const float* __restrict__ comp,
                       float* __restrict__ g_buf, float* __restrict__ kl)
{
    const int tid = threadIdx.x;
    if (tid == 0) kl[0] = (float)(-80076800.0 * 1.3244036413128371);
    for (int i = tid; i < 400; i += 256) {
        const int a = i / 20, b = i % 20;
        float s = 0.f;
#pragma unroll
        for (int c = 0; c < 20; c++) s += comp[a * 20 + c] * comp[b * 20 + c];
        g_buf[i] = s;
    }
}

__global__ __launch_bounds__(256, 4) void k_w(
    const float* __restrict__ comp, const float* __restrict__ g_buf,
    const float* __restrict__ wb0, const float* __restrict__ wd0,
    const float* __restrict__ wb1, const float* __restrict__ wd1,
    const float* __restrict__ wb2, const float* __restrict__ wd2,
    const float* __restrict__ wb3, const float* __restrict__ wd3,
    const float* __restrict__ wb4, const float* __restrict__ wd4,
    const float* __restrict__ wb5, const float* __restrict__ wd5,
    const float* __restrict__ wb6, const float* __restrict__ wd6,
    const int* __restrict__ regions_oi,
    __hip_bfloat162* __restrict__ w2,       // [256*20][4000] bf16 pairs
    float* __restrict__ s_part,             // [2048][20]
    float* __restrict__ kl_out)
{
    __shared__ float csT[400];    // csT[c*20+a] = comp[a*20+c]
    __shared__ float G_sh[400];   // G = C C^T
    __shared__ float red[4 * 20];
    __shared__ float klp[4];

    const int tid = threadIdx.x;
    const int r = blockIdx.x >> 3;
    const int tile = blockIdx.x & 7;
    const int base = tile * TBINS;

    for (int i = tid; i < 400; i += 256) {
        csT[i] = comp[(i % 20) * 20 + (i / 20)];
        G_sh[i] = g_buf[i];
    }
    const int r0 = regions_oi[r];
    __syncthreads();

    const float* __restrict__ p6 = wd6 + (size_t)r0 * (20 * 8000);
    const float* __restrict__ p5 = wd5 + (size_t)r0 * (20 * 4000);
    const float* __restrict__ p4 = wd4 + (size_t)r0 * (20 * 2000);
    const float* __restrict__ p3 = wd3 + (size_t)r0 * (20 * 1000);
    const float* __restrict__ p2 = wd2 + (size_t)r0 * (20 * 400);
    const float* __restrict__ p1 = wd1 + (size_t)r0 * (20 * 200);
    const float* __restrict__ p0 = wd0 + (size_t)r0 * (20 * 40);
    const float* __restrict__ b6 = wb6 + (size_t)r0 * 8000;
    const float* __restrict__ b5 = wb5 + (size_t)r0 * 4000;
    const float* __restrict__ b4 = wb4 + (size_t)r0 * 2000;
    const float* __restrict__ b3 = wb3 + (size_t)r0 * 1000;
    const float* __restrict__ b2 = wb2 + (size_t)r0 * 400;
    const float* __restrict__ b1 = wb1 + (size_t)r0 * 200;
    const float* __restrict__ b0 = wb0 + (size_t)r0 * 40;

    float q = 0.f;          // KL quadratic partial
    float sexp[20];
#pragma unroll
    for (int c = 0; c < 20; c++) sexp[c] = 0.f;

    // ---- pre-phase: KL quads for coarse levels 0..4 of this tile ----
    // per tile: L4:250 cols, L3:125, L2:50, L1:25, L0:5  => 455 units
#pragma unroll 1
    for (int it = 0; it < 2; ++it) {
        const int u = tid + it * 256;
        if (u < 455) {
            const float* P; int K, col;
            if (u < 250)      { P = p4; K = 2000; col = (base >> 2) + u; }
            else if (u < 375) { P = p3; K = 1000; col = (base >> 3) + u - 250; }
            else if (u < 425) { P = p2; K = 400;  col = base / 20 + u - 375; }
            else if (u < 450) { P = p1; K = 200;  col = base / 40 + u - 425; }
            else              { P = p0; K = 40;   col = base / 200 + u - 450; }
            float x[20];
            int off = col;
#pragma unroll
            for (int a = 0; a < 20; a++) { x[a] = P[off]; off += K; }
            QUADG(x);
        }
    }

    // ---- main loop: thread = 2 consecutive bins (j2 group), all 20 c ----
#pragma unroll 1
    for (int it = 0; it < 2; ++it) {
        const int jg = tid + it * 256;
        if (jg >= TBINS / 2) break;
        const int j = base + jg * 2;
        const int i5 = j >> 1, i4 = j >> 2, i3 = j >> 3;
        const int i2 = j / 20, i1 = j / 40, i0 = j / 200;

        // coarse sum (levels 0..4)
        float cs[20];
#pragma unroll
        for (int a = 0; a < 20; a++)
            cs[a] = p4[a * 2000 + i4] + p3[a * 1000 + i3] + p2[a * 400 + i2]
                  + p1[a * 200 + i1] + p0[a * 40 + i0];

        // level 5: quad + fold
        {
            float x[20];
#pragma unroll
            for (int a = 0; a < 20; a++) x[a] = p5[a * 4000 + i5];
            QUADG(x);
#pragma unroll
            for (int a = 0; a < 20; a++) cs[a] += x[a];
        }

        // level 6: two columns, quad each, then build u0/u1
        float u0[20], u1[20];
        {
            float x[20], y[20];
#pragma unroll
            for (int a = 0; a < 20; a++) {
                const float2 v = *(const float2*)(p6 + (size_t)a * 8000 + j);
                x[a] = v.x; y[a] = v.y;
            }
            QUADG(x);
#pragma unroll
            for (int a = 0; a < 20; a++) u0[a] = cs[a] + x[a];
            {
                float* x = y;   // alias for QUADG
                QUADG(x);
            }
#pragma unroll
            for (int a = 0; a < 20; a++) u1[a] = cs[a] + y[a];
        }

        // bias
        const float2 qb6 = *(const float2*)(b6 + j);
        const float bb = b5[i5] + b4[i4] + b3[i3] + b2[i2] + b1[i1] + b0[i0];
        const float bb0 = bb + qb6.x, bb1 = bb + qb6.y;

        __hip_bfloat162* wp = w2 + ((size_t)(r * 20) * 8000 + j) / 2;
#pragma unroll
        for (int c = 0; c < 20; c++) {
            float w0 = bb0, w1 = bb1;
            const float* cr = &csT[c * 20];
#pragma unroll
            for (int a = 0; a < 20; a++) {
                const float cc = cr[a];
                w0 += cc * u0[a]; w1 += cc * u1[a];
            }
            wp[(size_t)c * 4000] = __float22bfloat162_rn(make_float2(w0, w1));
            // |w| < ~2: unnormalized exp-sum safe in f32
            sexp[c] += __expf(w0) + __expf(w1);
        }
    }

    // ---- block reduction: sexp[20] and q ----
#pragma unroll
    for (int c = 0; c < 20; c++) {
        float s = sexp[c];
#pragma unroll
        for (int off = 32; off > 0; off >>= 1) s += __shfl_down(s, off, 64);
        if ((tid & 63) == 0) red[(tid >> 6) * 20 + c] = s;
    }
#pragma unroll
    for (int off = 32; off > 0; off >>= 1) q += __shfl_down(q, off, 64);
    if ((tid & 63) == 0) klp[tid >> 6] = q;
    __syncthreads();
    if (tid < 20)
        s_part[(size_t)blockIdx.x * 20 + tid] =
            red[tid] + red[20 + tid] + red[40 + tid] + red[60 + tid];
    if (tid == 0)
        atomicAdd(kl_out, (klp[0] + klp[1] + klp[2] + klp[3]) * (-0.5f / 2.25f));
}

__global__ void k_sub(const float* __restrict__ s_part, float* __restrict__ sub)
{
    const int i = blockIdx.x * 256 + threadIdx.x;
    if (i >= NROI * NC) return;
    const int r = i / 20, c = i % 20;
    float s = 0.f;
#pragma unroll
    for (int t = 0; t < NTILE; t++) s += s_part[(size_t)(r * NTILE + t) * 20 + c];
    sub[i] = logf(s) + 3.2188758248682006f;   // + log(25)
}

__global__ void k_gather(const int* __restrict__ lri, const int* __restrict__ lci,
                         const int* __restrict__ cli, const int* __restrict__ coords,
                         const __hip_bfloat16* __restrict__ w2,
                         const float* __restrict__ sub,
                         float* __restrict__ out)
{
    const int i = blockIdx.x * 256 + threadIdx.x;
    if (i >= NCUTS) return;
    const int r = lri[i];
    const int c = cli[lci[i]];
    int co = coords[i];
    co = co < 0 ? 0 : (co > 199999 ? 199999 : co);
    const int bin = co / 25;
    const int rc = r * 20 + c;
    out[i] = __bfloat162float(w2[(size_t)rc * 8000 + bin]) - sub[rc];
}

extern "C" void kernel_launch(void* const* d_in, const int* in_sizes, int n_in,
                              void* d_out, int out_size, void* d_ws, size_t ws_size,
                              hipStream_t stream)
{
    const float* comp = (const float*)d_in[0];
    const float* wb[7];
    const float* wd[7];
    if (in_sizes[2] == 400000) {
        for (int l = 0; l < 7; l++) { wb[l] = (const float*)d_in[1 + 2 * l]; wd[l] = (const float*)d_in[2 + 2 * l]; }
    } else {
        for (int l = 0; l < 7; l++) { wb[l] = (const float*)d_in[1 + l]; wd[l] = (const float*)d_in[8 + l]; }
    }
    const int* regions_oi = (const int*)d_in[15];
    const int* lri   = (const int*)d_in[16];
    const int* lci   = (const int*)d_in[17];
    const int* cli   = (const int*)d_in[18];
    const int* coords= (const int*)d_in[19];
    float* out = (float*)d_out;

    // workspace layout
    __hip_bfloat16* w2 = (__hip_bfloat16*)d_ws;                   // 256*20*8000 bf16 = 81.92 MB
    float* s_part = (float*)(w2 + (size_t)NROI * NC * NFINAL);    // 2048*20 f32
    float* sub    = s_part + 2048 * 20;                           // 5120 f32
    float* g_buf  = sub + NROI * NC;                              // 400 f32
    const size_t need = (size_t)NROI * NC * NFINAL * 2
                      + (2048 * 20 + NROI * NC + 400) * sizeof(float);
    if (ws_size < need) return;

    k_init<<<1, 256, 0, stream>>>(comp, g_buf, out + NCUTS);
    k_w<<<NROI * NTILE, 256, 0, stream>>>(comp, g_buf,
        wb[0], wd[0], wb[1], wd[1], wb[2], wd[2], wb[3], wd[3],
        wb[4], wd[4], wb[5], wd[5], wb[6], wd[6],
        regions_oi, (__hip_bfloat162*)w2, s_part, out + NCUTS);
    k_sub<<<(NROI * NC + 255) / 256, 256, 0, stream>>>(s_part, sub);
    k_gather<<<(NCUTS + 255) / 256, 256, 0, stream>>>(lri, lci, cli, coords,
        w2, sub, out);
}

// Round 4
// 660.609 us; speedup vs baseline: 3.1827x; 3.1827x over previous
//
#include <hip/hip_runtime.h>
#include <hip/hip_bf16.h>
#include <math.h>

// SharedLora on MI355X — round 4.
// Round-3 lesson (twice): per-thread 20-vector state spills; keep it in LDS.
// Single fused k_w per (region, 200-bin tile):
//   P0: stage raw level tiles a-major in LDS (L6..L0), bias sum, csT, G=CC^T
//   P1: KL quads per column: q += x^T G x  (x[20] streamed from LDS)
//   P2: fold level sum IN PLACE into L6 tile -> U[a][j]
//   P3: w[c][j] = bias[j] + sum_a csT[c][a] U[a][j]; bf16 store + exp-sum
// KL second pass deleted; w stored bf16 (L3-resident for gather).

#define NROI 256
#define NC 20
#define NFINAL 8000
#define NCUTS 500000
#define TBINS 200
#define NTILE 40           // 8000 / TBINS

// LDS float offsets (all %4==0 for b128 alignment)
#define L6O 0        // 20 x 200
#define L5O 4000     // 20 x 100
#define L4O 6000     // 20 x 50
#define L3O 7000     // 20 x 25
#define L2O 7500     // 20 x 10
#define L1O 7700     // 20 x 5
#define L0O 7800     // 20 x 1
#define BIO 7820     // 200 bias
#define CTO 8020     // 400 csT[c*20+a]
#define GO  8420     // 400 G
#define SHF 8820

__global__ void k_init(const float* __restrict__ comp,
                       float* __restrict__ g_buf, float* __restrict__ kl)
{
    const int tid = threadIdx.x;
    if (tid == 0) kl[0] = (float)(-80076800.0 * 1.3244036413128371);
    for (int i = tid; i < 400; i += 256) {
        const int a = i / 20, b = i % 20;
        float s = 0.f;
#pragma unroll
        for (int c = 0; c < 20; c++) s += comp[a * 20 + c] * comp[b * 20 + c];
        g_buf[i] = s;
    }
}

__global__ __launch_bounds__(256) void k_w(
    const float* __restrict__ comp, const float* __restrict__ g_buf,
    const float* __restrict__ wb0, const float* __restrict__ wd0,
    const float* __restrict__ wb1, const float* __restrict__ wd1,
    const float* __restrict__ wb2, const float* __restrict__ wd2,
    const float* __restrict__ wb3, const float* __restrict__ wd3,
    const float* __restrict__ wb4, const float* __restrict__ wd4,
    const float* __restrict__ wb5, const float* __restrict__ wd5,
    const float* __restrict__ wb6, const float* __restrict__ wd6,
    const int* __restrict__ regions_oi,
    __hip_bfloat16* __restrict__ w2,
    float* __restrict__ s_part, float* __restrict__ kl_out)
{
    __shared__ float sh[SHF];
    __shared__ float sexp_sh[20];
    __shared__ float klp[4];

    const int tid = threadIdx.x;
    const int r = blockIdx.x / NTILE;
    const int tile = blockIdx.x - r * NTILE;
    const int base = tile * TBINS;
    const int r0 = regions_oi[r];

    const float* __restrict__ p6 = wd6 + (size_t)r0 * (20 * 8000);
    const float* __restrict__ p5 = wd5 + (size_t)r0 * (20 * 4000);
    const float* __restrict__ p4 = wd4 + (size_t)r0 * (20 * 2000);
    const float* __restrict__ p3 = wd3 + (size_t)r0 * (20 * 1000);
    const float* __restrict__ p2 = wd2 + (size_t)r0 * (20 * 400);
    const float* __restrict__ p1 = wd1 + (size_t)r0 * (20 * 200);
    const float* __restrict__ p0 = wd0 + (size_t)r0 * (20 * 40);
    const float* __restrict__ b6 = wb6 + (size_t)r0 * 8000;
    const float* __restrict__ b5 = wb5 + (size_t)r0 * 4000;
    const float* __restrict__ b4 = wb4 + (size_t)r0 * 2000;
    const float* __restrict__ b3 = wb3 + (size_t)r0 * 1000;
    const float* __restrict__ b2 = wb2 + (size_t)r0 * 400;
    const float* __restrict__ b1 = wb1 + (size_t)r0 * 200;
    const float* __restrict__ b0 = wb0 + (size_t)r0 * 40;

    // ---- P0: stage ----
    for (int i = tid; i < 400; i += 256) {
        sh[CTO + i] = comp[(i % 20) * 20 + (i / 20)];
        sh[GO + i] = g_buf[i];
    }
    if (tid < 20) sexp_sh[tid] = 0.f;

    // float4 staging: L6 (1000 units) + L5 (500 units)
#pragma unroll 1
    for (int it = 0; it < 6; it++) {
        const int u = it * 256 + tid;
        if (u >= 1500) break;
        if (u < 1000) {
            const int a = u / 50, g = u - a * 50;
            const float4 v = *(const float4*)(p6 + (size_t)a * 8000 + base + 4 * g);
            *(float4*)(&sh[L6O + a * 200 + 4 * g]) = v;
        } else {
            const int v_ = u - 1000;
            const int a = v_ / 25, g = v_ - a * 25;
            const float4 v = *(const float4*)(p5 + (size_t)a * 4000 + (base >> 1) + 4 * g);
            *(float4*)(&sh[L5O + a * 100 + 4 * g]) = v;
        }
    }
    // scalar staging: L4 1000, L3 500, L2 200, L1 100, L0 20  => 1820
#pragma unroll 1
    for (int it = 0; it < 8; it++) {
        const int u = it * 256 + tid;
        if (u >= 1820) break;
        if (u < 1000) {
            const int a = u / 50, c = u - a * 50;
            sh[L4O + a * 50 + c] = p4[a * 2000 + (base >> 2) + c];
        } else if (u < 1500) {
            const int v_ = u - 1000; const int a = v_ / 25, c = v_ - a * 25;
            sh[L3O + a * 25 + c] = p3[a * 1000 + (base >> 3) + c];
        } else if (u < 1700) {
            const int v_ = u - 1500; const int a = v_ / 10, c = v_ - a * 10;
            sh[L2O + a * 10 + c] = p2[a * 400 + base / 20 + c];
        } else if (u < 1800) {
            const int v_ = u - 1700; const int a = v_ / 5, c = v_ - a * 5;
            sh[L1O + a * 5 + c] = p1[a * 200 + base / 40 + c];
        } else {
            const int a = u - 1800;
            sh[L0O + a] = p0[a * 40 + base / 200];
        }
    }
    // bias (folded across all 7 levels)
    if (tid < TBINS) {
        const int j = base + tid;
        sh[BIO + tid] = b6[j] + b5[j >> 1] + b4[j >> 2] + b3[j >> 3]
                      + b2[j / 20] + b1[j / 40] + b0[j / 200];
    }
    __syncthreads();

    // ---- P1: KL quads over 391 columns ----
    float q = 0.f;
#pragma unroll 1
    for (int it = 0; it < 2; it++) {
        const int u = it * 256 + tid;
        if (u >= 391) break;
        int off, stride;
        if (u < 200)      { off = L6O + u;        stride = 200; }
        else if (u < 300) { off = L5O + (u - 200); stride = 100; }
        else if (u < 350) { off = L4O + (u - 300); stride = 50; }
        else if (u < 375) { off = L3O + (u - 350); stride = 25; }
        else if (u < 385) { off = L2O + (u - 375); stride = 10; }
        else if (u < 390) { off = L1O + (u - 385); stride = 5; }
        else              { off = L0O;             stride = 1; }
        float x[20];
        int ad = off;
#pragma unroll
        for (int a = 0; a < 20; a++) { x[a] = sh[ad]; ad += stride; }
#pragma unroll
        for (int a = 0; a < 20; a++) {
            float t = 0.f;
#pragma unroll
            for (int b = 0; b < 20; b++) t += sh[GO + a * 20 + b] * x[b];
            q += x[a] * t;
        }
    }
#pragma unroll
    for (int off = 32; off > 0; off >>= 1) q += __shfl_down(q, off, 64);
    if ((tid & 63) == 0) klp[tid >> 6] = q;
    __syncthreads();   // P1 done before P2 overwrites L6

    // ---- P2: fold coarse levels into L6 in place -> U ----
#pragma unroll 1
    for (int it = 0; it < 4; it++) {
        if (tid >= 250) break;
        const int a = it * 5 + tid / 50;
        const int g = tid % 50;
        float4 u6 = *(const float4*)(&sh[L6O + a * 200 + 4 * g]);
        const float2 v5 = *(const float2*)(&sh[L5O + a * 100 + 2 * g]);
        const float cs = sh[L4O + a * 50 + g] + sh[L3O + a * 25 + (g >> 1)]
                       + sh[L2O + a * 10 + g / 5] + sh[L1O + a * 5 + g / 10]
                       + sh[L0O + a];
        const float c01 = cs + v5.x, c23 = cs + v5.y;
        u6.x += c01; u6.y += c01; u6.z += c23; u6.w += c23;
        *(float4*)(&sh[L6O + a * 200 + 4 * g]) = u6;
    }
    __syncthreads();

    // ---- P3: w = bias + csT . U ; bf16 store + exp-sum ----
#pragma unroll 1
    for (int it = 0; it < 4; it++) {
        if (tid >= 250) break;
        const int c = it * 5 + tid / 50;
        const int g = tid % 50;
        const float4 bi = *(const float4*)(&sh[BIO + 4 * g]);
        float4 acc = bi;
#pragma unroll
        for (int a = 0; a < 20; a++) {
            const float cc = sh[CTO + c * 20 + a];
            const float4 u = *(const float4*)(&sh[L6O + a * 200 + 4 * g]);
            acc.x += cc * u.x; acc.y += cc * u.y;
            acc.z += cc * u.z; acc.w += cc * u.w;
        }
        union { __hip_bfloat162 h2[2]; uint2 u2; } pk;
        pk.h2[0] = __float22bfloat162_rn(make_float2(acc.x, acc.y));
        pk.h2[1] = __float22bfloat162_rn(make_float2(acc.z, acc.w));
        *(uint2*)(w2 + (size_t)(r * 20 + c) * 8000 + base + 4 * g) = pk.u2;
        const float es = __expf(acc.x) + __expf(acc.y) + __expf(acc.z) + __expf(acc.w);
        atomicAdd(&sexp_sh[c], es);
    }
    __syncthreads();

    if (tid < 20) s_part[(size_t)blockIdx.x * 20 + tid] = sexp_sh[tid];
    if (tid == 0)
        atomicAdd(kl_out, (klp[0] + klp[1] + klp[2] + klp[3]) * (-0.5f / 2.25f));
}

__global__ void k_sub(const float* __restrict__ s_part, float* __restrict__ sub)
{
    const int i = blockIdx.x * 256 + threadIdx.x;
    if (i >= NROI * NC) return;
    const int r = i / 20, c = i % 20;
    float s = 0.f;
#pragma unroll 1
    for (int t = 0; t < NTILE; t++) s += s_part[(size_t)(r * NTILE + t) * 20 + c];
    sub[i] = logf(s) + 3.2188758248682006f;   // + log(25)
}

__global__ void k_gather(const int* __restrict__ lri, const int* __restrict__ lci,
                         const int* __restrict__ cli, const int* __restrict__ coords,
                         const __hip_bfloat16* __restrict__ w2,
                         const float* __restrict__ sub,
                         float* __restrict__ out)
{
    const int i = blockIdx.x * 256 + threadIdx.x;
    if (i >= NCUTS) return;
    const int r = lri[i];
    const int c = cli[lci[i]];
    int co = coords[i];
    co = co < 0 ? 0 : (co > 199999 ? 199999 : co);
    const int bin = co / 25;
    const int rc = r * 20 + c;
    out[i] = __bfloat162float(w2[(size_t)rc * 8000 + bin]) - sub[rc];
}

extern "C" void kernel_launch(void* const* d_in, const int* in_sizes, int n_in,
                              void* d_out, int out_size, void* d_ws, size_t ws_size,
                              hipStream_t stream)
{
    const float* comp = (const float*)d_in[0];
    const float* wb[7];
    const float* wd[7];
    if (in_sizes[2] == 400000) {
        for (int l = 0; l < 7; l++) { wb[l] = (const float*)d_in[1 + 2 * l]; wd[l] = (const float*)d_in[2 + 2 * l]; }
    } else {
        for (int l = 0; l < 7; l++) { wb[l] = (const float*)d_in[1 + l]; wd[l] = (const float*)d_in[8 + l]; }
    }
    const int* regions_oi = (const int*)d_in[15];
    const int* lri   = (const int*)d_in[16];
    const int* lci   = (const int*)d_in[17];
    const int* cli   = (const int*)d_in[18];
    const int* coords= (const int*)d_in[19];
    float* out = (float*)d_out;

    __hip_bfloat16* w2 = (__hip_bfloat16*)d_ws;                     // 81.92 MB
    float* s_part = (float*)(w2 + (size_t)NROI * NC * NFINAL);      // 10240*20 f32
    float* sub    = s_part + (size_t)NROI * NTILE * 20;             // 5120 f32
    float* g_buf  = sub + NROI * NC;                                // 400 f32
    const size_t need = (size_t)NROI * NC * NFINAL * 2
                      + ((size_t)NROI * NTILE * 20 + NROI * NC + 400) * sizeof(float);
    if (ws_size < need) return;

    k_init<<<1, 256, 0, stream>>>(comp, g_buf, out + NCUTS);
    k_w<<<NROI * NTILE, 256, 0, stream>>>(comp, g_buf,
        wb[0], wd[0], wb[1], wd[1], wb[2], wd[2], wb[3], wd[3],
        wb[4], wd[4], wb[5], wd[5], wb[6], wd[6],
        regions_oi, w2, s_part, out + NCUTS);
    k_sub<<<(NROI * NC + 255) / 256, 256, 0, stream>>>(s_part, sub);
    k_gather<<<(NCUTS + 255) / 256, 256, 0, stream>>>(lri, lci, cli, coords,
        w2, sub, out);
}

// Round 5
// 346.334 us; speedup vs baseline: 6.0709x; 1.9074x over previous
//
#include <hip/hip_runtime.h>
#include <hip/hip_bf16.h>
#include <math.h>

// SharedLora on MI355X — round 5: no-LDS, thread-per-bin-pair design.
// Lessons: r1/r3 = per-thread arrays >~100 floats spill; r4 = LDS-port-bound
// (G-from-LDS inner loop). Here: thread = 2 fine bins; all delta loads are
// naturally coalesced GLOBAL loads (L1 absorbs rep-fold reuse); comp is read
// with wave-uniform indices -> scalar loads (s_load, K$), costing no VALU/LDS.
// w_c = bias + y6 + y5 + ycs per level-projection; KL quads = y^2 in the same
// registers (Gram/y-form). L4/L3 quads: compact L1-hot phase B, same block.
// L0-2 quads (13 MB): tiny k_klc. w stored bf16 (L3-resident for gather).

#define NROI 256
#define NC 20
#define NFINAL 8000
#define NCUTS 500000
#define TBINS 500
#define NTILE 16           // 8000 / TBINS

// q += sum_c (sum_a comp[a][c] * x[a])^2   (comp via uniform scalar loads)
#define YQUAD(x)                                            \
    do {                                                    \
        _Pragma("unroll")                                   \
        for (int c_ = 0; c_ < 20; c_++) {                   \
            float y_ = 0.f;                                 \
            _Pragma("unroll")                               \
            for (int a_ = 0; a_ < 20; a_++)                 \
                y_ += comp[a_ * 20 + c_] * x[a_];           \
            q += y_ * y_;                                   \
        }                                                   \
    } while (0)

__global__ void k_init(float* __restrict__ kl)
{
    // count = 256*20*15640 = 80,076,800 ; per-elem const = -(log1.5+0.5*log(2pi))
    kl[0] = (float)(-80076800.0 * 1.3244036413128371);
}

__global__ __launch_bounds__(256, 2) void k_main(
    const float* __restrict__ comp,
    const float* __restrict__ wb0, const float* __restrict__ wd0,
    const float* __restrict__ wb1, const float* __restrict__ wd1,
    const float* __restrict__ wb2, const float* __restrict__ wd2,
    const float* __restrict__ wb3, const float* __restrict__ wd3,
    const float* __restrict__ wb4, const float* __restrict__ wd4,
    const float* __restrict__ wb5, const float* __restrict__ wd5,
    const float* __restrict__ wb6, const float* __restrict__ wd6,
    const int* __restrict__ regions_oi,
    __hip_bfloat16* __restrict__ w2,
    float* __restrict__ s_part, float* __restrict__ kl_out)
{
    __shared__ float red[4 * 20];
    __shared__ float klp[4];

    const int tid = threadIdx.x;
    const int r = blockIdx.x >> 4;
    const int tile = blockIdx.x & 15;
    const int base = tile * TBINS;
    const int r0 = regions_oi[r];

    const float* __restrict__ p6 = wd6 + (size_t)r0 * (20 * 8000);
    const float* __restrict__ p5 = wd5 + (size_t)r0 * (20 * 4000);
    const float* __restrict__ p4 = wd4 + (size_t)r0 * (20 * 2000);
    const float* __restrict__ p3 = wd3 + (size_t)r0 * (20 * 1000);
    const float* __restrict__ p2 = wd2 + (size_t)r0 * (20 * 400);
    const float* __restrict__ p1 = wd1 + (size_t)r0 * (20 * 200);
    const float* __restrict__ p0 = wd0 + (size_t)r0 * (20 * 40);
    const float* __restrict__ b6 = wb6 + (size_t)r0 * 8000;
    const float* __restrict__ b5 = wb5 + (size_t)r0 * 4000;
    const float* __restrict__ b4 = wb4 + (size_t)r0 * 2000;
    const float* __restrict__ b3 = wb3 + (size_t)r0 * 1000;
    const float* __restrict__ b2 = wb2 + (size_t)r0 * 400;
    const float* __restrict__ b1 = wb1 + (size_t)r0 * 200;
    const float* __restrict__ b0 = wb0 + (size_t)r0 * 40;

    float q = 0.f;
    float sexp[20];
#pragma unroll
    for (int c = 0; c < 20; c++) sexp[c] = 0.f;

    // ---- phase A: w for 2 bins + L6/L5 quads ----
    if (tid < TBINS / 2) {
        const int j = base + 2 * tid;
        const int i5 = j >> 1, i4 = j >> 2, i3 = j >> 3;
        const int i2 = j / 20, i1 = j / 40, i0 = j / 200;

        float2 x6[20];
        float x5[20];
        float cs[20];
#pragma unroll
        for (int a = 0; a < 20; a++)
            x6[a] = *(const float2*)(p6 + (size_t)a * 8000 + j);
#pragma unroll
        for (int a = 0; a < 20; a++) x5[a] = p5[a * 4000 + i5];
#pragma unroll
        for (int a = 0; a < 20; a++)
            cs[a] = p4[a * 2000 + i4] + p3[a * 1000 + i3] + p2[a * 400 + i2]
                  + p1[a * 200 + i1] + p0[a * 40 + i0];

        const float2 bw6 = *(const float2*)(b6 + j);
        const float bb = b5[i5] + b4[i4] + b3[i3] + b2[i2] + b1[i1] + b0[i0];
        const float bb0 = bb + bw6.x, bb1 = bb + bw6.y;

        __hip_bfloat162* wp = (__hip_bfloat162*)(w2 + (size_t)(r * 20) * 8000 + j);
#pragma unroll
        for (int c = 0; c < 20; c++) {
            float y6a = 0.f, y6b = 0.f, y5 = 0.f, ycs = 0.f;
#pragma unroll
            for (int a = 0; a < 20; a++) {
                const float cc = comp[a * 20 + c];   // uniform -> s_load
                y6a += cc * x6[a].x; y6b += cc * x6[a].y;
                y5  += cc * x5[a];   ycs += cc * cs[a];
            }
            q += y6a * y6a + y6b * y6b + y5 * y5;
            const float t = y5 + ycs;
            const float wa = bb0 + y6a + t;
            const float wb = bb1 + y6b + t;
            wp[(size_t)c * 4000] = __float22bfloat162_rn(make_float2(wa, wb));
            // |w| small (~<4): unnormalized exp-sum safe in f32
            sexp[c] += __expf(wa) + __expf(wb);
        }
    }

    // ---- phase B: L4 / L3 quads (compact, L1-hot re-read) ----
    if (tid < 128) {
        if (tid < 125) {                       // L4: 125 cols per tile
            const int col = tile * 125 + tid;
            float x[20];
#pragma unroll
            for (int a = 0; a < 20; a++) x[a] = p4[a * 2000 + col];
            YQUAD(x);
        }
    } else {
        const int lo = (TBINS * tile + 7) >> 3;          // L3 cols [lo, hi)
        const int hi = (TBINS * tile + TBINS + 7) >> 3;
        const int u = tid - 128;
        if (u < hi - lo) {
            const int col = lo + u;
            float x[20];
#pragma unroll
            for (int a = 0; a < 20; a++) x[a] = p3[a * 1000 + col];
            YQUAD(x);
        }
    }

    // ---- reductions ----
#pragma unroll
    for (int c = 0; c < 20; c++) {
        float s = sexp[c];
#pragma unroll
        for (int off = 32; off > 0; off >>= 1) s += __shfl_down(s, off, 64);
        if ((tid & 63) == 0) red[(tid >> 6) * 20 + c] = s;
    }
#pragma unroll
    for (int off = 32; off > 0; off >>= 1) q += __shfl_down(q, off, 64);
    if ((tid & 63) == 0) klp[tid >> 6] = q;
    __syncthreads();
    if (tid < 20)
        s_part[(size_t)blockIdx.x * 20 + tid] =
            red[tid] + red[20 + tid] + red[40 + tid] + red[60 + tid];
    if (tid == 0)
        atomicAdd(kl_out, (klp[0] + klp[1] + klp[2] + klp[3]) * (-0.5f / 2.25f));
}

// KL quads for levels 0..2 (40+200+400 = 640 cols per region, 13 MB total)
__global__ __launch_bounds__(256, 2) void k_klc(
    const float* __restrict__ comp,
    const float* __restrict__ wd0, const float* __restrict__ wd1,
    const float* __restrict__ wd2,
    const int* __restrict__ regions_oi, float* __restrict__ kl_out)
{
    __shared__ float klp[4];
    const int tid = threadIdx.x;
    const int r0 = regions_oi[blockIdx.x];
    const float* __restrict__ p2 = wd2 + (size_t)r0 * (20 * 400);
    const float* __restrict__ p1 = wd1 + (size_t)r0 * (20 * 200);
    const float* __restrict__ p0 = wd0 + (size_t)r0 * (20 * 40);

    float q = 0.f;
#pragma unroll 1
    for (int it = 0; it < 3; it++) {
        const int u = it * 256 + tid;
        if (u >= 640) break;
        const float* P; int K, col;
        if (u < 400)      { P = p2; K = 400; col = u; }
        else if (u < 600) { P = p1; K = 200; col = u - 400; }
        else              { P = p0; K = 40;  col = u - 600; }
        float x[20];
#pragma unroll
        for (int a = 0; a < 20; a++) x[a] = P[a * K + col];
        YQUAD(x);
    }
#pragma unroll
    for (int off = 32; off > 0; off >>= 1) q += __shfl_down(q, off, 64);
    if ((tid & 63) == 0) klp[tid >> 6] = q;
    __syncthreads();
    if (tid == 0)
        atomicAdd(kl_out, (klp[0] + klp[1] + klp[2] + klp[3]) * (-0.5f / 2.25f));
}

__global__ void k_sub(const float* __restrict__ s_part, float* __restrict__ sub)
{
    const int i = blockIdx.x * 256 + threadIdx.x;
    if (i >= NROI * NC) return;
    const int r = i / 20, c = i % 20;
    float s = 0.f;
#pragma unroll 1
    for (int t = 0; t < NTILE; t++) s += s_part[(size_t)(r * NTILE + t) * 20 + c];
    sub[i] = logf(s) + 3.2188758248682006f;   // + log(25)
}

__global__ void k_gather(const int* __restrict__ lri, const int* __restrict__ lci,
                         const int* __restrict__ cli, const int* __restrict__ coords,
                         const __hip_bfloat16* __restrict__ w2,
                         const float* __restrict__ sub,
                         float* __restrict__ out)
{
    const int i = blockIdx.x * 256 + threadIdx.x;
    if (i >= NCUTS) return;
    const int r = lri[i];
    const int c = cli[lci[i]];
    int co = coords[i];
    co = co < 0 ? 0 : (co > 199999 ? 199999 : co);
    const int bin = co / 25;
    const int rc = r * 20 + c;
    out[i] = __bfloat162float(w2[(size_t)rc * 8000 + bin]) - sub[rc];
}

extern "C" void kernel_launch(void* const* d_in, const int* in_sizes, int n_in,
                              void* d_out, int out_size, void* d_ws, size_t ws_size,
                              hipStream_t stream)
{
    const float* comp = (const float*)d_in[0];
    const float* wb[7];
    const float* wd[7];
    if (in_sizes[2] == 400000) {
        for (int l = 0; l < 7; l++) { wb[l] = (const float*)d_in[1 + 2 * l]; wd[l] = (const float*)d_in[2 + 2 * l]; }
    } else {
        for (int l = 0; l < 7; l++) { wb[l] = (const float*)d_in[1 + l]; wd[l] = (const float*)d_in[8 + l]; }
    }
    const int* regions_oi = (const int*)d_in[15];
    const int* lri   = (const int*)d_in[16];
    const int* lci   = (const int*)d_in[17];
    const int* cli   = (const int*)d_in[18];
    const int* coords= (const int*)d_in[19];
    float* out = (float*)d_out;

    __hip_bfloat16* w2 = (__hip_bfloat16*)d_ws;                     // 81.92 MB
    float* s_part = (float*)(w2 + (size_t)NROI * NC * NFINAL);      // 4096*20 f32
    float* sub    = s_part + (size_t)NROI * NTILE * 20;             // 5120 f32
    const size_t need = (size_t)NROI * NC * NFINAL * 2
                      + ((size_t)NROI * NTILE * 20 + NROI * NC) * sizeof(float);
    if (ws_size < need) return;

    k_init<<<1, 1, 0, stream>>>(out + NCUTS);
    k_main<<<NROI * NTILE, 256, 0, stream>>>(comp,
        wb[0], wd[0], wb[1], wd[1], wb[2], wd[2], wb[3], wd[3],
        wb[4], wd[4], wb[5], wd[5], wb[6], wd[6],
        regions_oi, w2, s_part, out + NCUTS);
    k_klc<<<NROI, 256, 0, stream>>>(comp, wd[0], wd[1], wd[2],
        regions_oi, out + NCUTS);
    k_sub<<<(NROI * NC + 255) / 256, 256, 0, stream>>>(s_part, sub);
    k_gather<<<(NCUTS + 255) / 256, 256, 0, stream>>>(lri, lci, cli, coords,
        w2, sub, out);
}